// Round 10
// baseline (628.208 us; speedup 1.0000x reference)
//
#include <hip/hip_runtime.h>
#include <cstdint>
#include <cstddef>

#define BB 16
#define NN 512
#define FF 256
#define NC 32
#define KITERS 10
#define CCITERS 20
#define MAXD 96    // cap for full-adjacency neighbor list (mean deg ~20)
#define FMAXD 64   // cap for same-concept filtered list

typedef __attribute__((ext_vector_type(4))) double double4_t;

// ---------- adjacency bits + neighbor list + degree normalization ----------
__global__ __launch_bounds__(64) void build_adjbits(const float* __restrict__ adj,
                                                    unsigned long long* __restrict__ adjbits,
                                                    double* __restrict__ dinv,
                                                    unsigned short* __restrict__ nbr,
                                                    int* __restrict__ degv) {
  int i = blockIdx.x, b = blockIdx.y, lane = threadIdx.x;
  const float* row = adj + ((size_t)(b * NN + i)) * NN;
  unsigned long long lmask = (1ULL << lane) - 1ULL;
  int base = 0;
#pragma unroll
  for (int q = 0; q < 8; ++q) {
    bool pred = (row[q * 64 + lane] != 0.0f);
    unsigned long long m = __ballot(pred ? 1 : 0);
    if (lane == 0) adjbits[((size_t)(b * NN + i)) * 8 + q] = m;
    if (pred) {
      int pos = base + __popcll(m & lmask);
      if (pos < MAXD) nbr[((size_t)(b * NN + i)) * MAXD + pos] = (unsigned short)(q * 64 + lane);
    }
    base += __popcll(m);
  }
  if (lane == 0) {
    degv[b * NN + i] = base;
    double tot = (double)base + 1.0;  // a = adj + I; clip no-op since >=1
    dinv[b * NN + i] = 1.0 / sqrt(tot);
  }
}

// ---------- GEMM: Y[b] = dinv_row * (X[b] @ W), fp64 accumulate (R8-proven scalar) ----------
__global__ __launch_bounds__(256) void gemm_scale(const float* __restrict__ X,
                                                  const float* __restrict__ W,
                                                  const double* __restrict__ dinv,
                                                  float* __restrict__ Y) {
  __shared__ float As[16][68];
  __shared__ float Bs[16][64];
  int bm = blockIdx.x, bn = blockIdx.y, b = blockIdx.z;
  int tid = threadIdx.x;
  int tx = tid & 15, ty = tid >> 4;
  const float* Xb = X + (size_t)b * NN * FF;
  float* Yb = Y + (size_t)b * NN * FF;
  double acc[4][4] = {};
  for (int kt = 0; kt < FF; kt += 16) {
    {
      int m = tid >> 2, kq = (tid & 3) * 4;
      const float4 v = *(const float4*)&Xb[(size_t)(bm * 64 + m) * FF + kt + kq];
      As[kq + 0][m] = v.x; As[kq + 1][m] = v.y; As[kq + 2][m] = v.z; As[kq + 3][m] = v.w;
    }
    {
      int k = tid >> 4, n4 = (tid & 15) * 4;
      *(float4*)&Bs[k][n4] = *(const float4*)&W[(size_t)(kt + k) * FF + bn * 64 + n4];
    }
    __syncthreads();
#pragma unroll
    for (int k = 0; k < 16; ++k) {
      float4 a = *(const float4*)&As[k][ty * 4];
      float4 bv = *(const float4*)&Bs[k][tx * 4];
      double ax = a.x, ay = a.y, az = a.z, aw = a.w;
      double bx = bv.x, by = bv.y, bz = bv.z, bw = bv.w;
      acc[0][0] += ax * bx; acc[0][1] += ax * by; acc[0][2] += ax * bz; acc[0][3] += ax * bw;
      acc[1][0] += ay * bx; acc[1][1] += ay * by; acc[1][2] += ay * bz; acc[1][3] += ay * bw;
      acc[2][0] += az * bx; acc[2][1] += az * by; acc[2][2] += az * bz; acc[2][3] += az * bw;
      acc[3][0] += aw * bx; acc[3][1] += aw * by; acc[3][2] += aw * bz; acc[3][3] += aw * bw;
    }
    __syncthreads();
  }
#pragma unroll
  for (int i = 0; i < 4; ++i) {
    int row = bm * 64 + ty * 4 + i;
    double di = dinv[b * NN + row];
    float4 v;
    v.x = (float)(di * acc[i][0]); v.y = (float)(di * acc[i][1]);
    v.z = (float)(di * acc[i][2]); v.w = (float)(di * acc[i][3]);
    *(float4*)&Yb[(size_t)row * FF + bn * 64 + tx * 4] = v;
  }
}

// ---------- SpMV + optional (p2 / cent0 / kmeans-buffer zeroing) ----------
__global__ __launch_bounds__(256) void spmv_relu(const float* __restrict__ Y,
                                                 const unsigned short* __restrict__ nbr,
                                                 const int* __restrict__ degv,
                                                 const unsigned long long* __restrict__ adjbits,
                                                 const double* __restrict__ dinv,
                                                 const float* __restrict__ bias,
                                                 float* __restrict__ H,
                                                 double* __restrict__ p2out,
                                                 double* __restrict__ cent0,
                                                 char* __restrict__ zbuf,
                                                 int zchunks) {
  __shared__ double red[256];
  int i = blockIdx.x, b = blockIdx.y, f = threadIdx.x;
  int row = b * NN + i;
  const float* Yb = Y + (size_t)b * NN * FF;
  double z = (double)Yb[(size_t)i * FF + f];  // +I term
  int deg = degv[row];
  if (deg <= MAXD) {
    const unsigned short* lst = nbr + (size_t)row * MAXD;
    int n = 0;
    for (; n + 4 <= deg; n += 4) {
      int j0 = lst[n], j1 = lst[n + 1], j2 = lst[n + 2], j3 = lst[n + 3];
      float v0 = Yb[(size_t)j0 * FF + f];
      float v1 = Yb[(size_t)j1 * FF + f];
      float v2 = Yb[(size_t)j2 * FF + f];
      float v3 = Yb[(size_t)j3 * FF + f];
      z += (double)v0; z += (double)v1; z += (double)v2; z += (double)v3;
    }
    for (; n < deg; ++n) z += (double)Yb[(size_t)lst[n] * FF + f];
  } else {
    const unsigned long long* brow = adjbits + (size_t)row * 8;
    for (int q = 0; q < 8; ++q) {
      unsigned long long bits = brow[q];
      while (bits) {
        int j = (q << 6) + __builtin_ctzll(bits);
        bits &= bits - 1;
        z += (double)Yb[(size_t)j * FF + f];
      }
    }
  }
  double h = dinv[row] * z + (double)bias[f];
  float hf = (h > 0.0) ? (float)h : 0.0f;
  H[((size_t)row) * FF + f] = hf;

  if (p2out) {  // uniform branch (kernel arg)
    double v = (double)hf;
    red[f] = v * v;
    __syncthreads();
    for (int s = 128; s; s >>= 1) { if (f < s) red[f] += red[f + s]; __syncthreads(); }
    if (f == 0) p2out[row] = red[0];
    if (b == 0 && i < NC) cent0[i * FF + f] = (double)hf;
    if (b == 2 || b == 3) {  // zero kmeans accumulators (dead h1 region)
      int chunk = (b - 2) * 512 + i;
      if (chunk < zchunks) {
        float4 z4 = {0.f, 0.f, 0.f, 0.f};
        ((float4*)(zbuf + (size_t)chunk * 4096))[f] = z4;
      }
    }
  }
}

// ---------- kmeans iteration: centroid recompute + MFMA d2 + argmin + replica atomics ----------
__global__ __launch_bounds__(256) void kmeans_it(const float* __restrict__ pts,
                                                 const double* __restrict__ cent0,
                                                 double* __restrict__ centprev,
                                                 double* __restrict__ cent_sum4,
                                                 int* __restrict__ cntI,
                                                 const double* __restrict__ p2,
                                                 int* __restrict__ assignI,
                                                 float* __restrict__ conceptsF,
                                                 int it) {
  __shared__ float ps[32][260];
  __shared__ double csT[256][35];    // csT[k][c]; reused as acc[32][258]
  __shared__ double d2s[32][33];
  __shared__ double c2s[32];
  __shared__ double cinv[32];
  __shared__ double want[3];
  __shared__ double probe_raw[2][2];
  __shared__ int as[32];
  __shared__ int lcs[32];
  __shared__ int hyp;
  int g = blockIdx.x, tid = threadIdx.x;

  for (int r = 0; r < 32; ++r) ps[r][tid] = pts[(size_t)(g * 32 + r) * FF + tid];
  if (it > 0 && tid < 32) {
    int ct = cntI[(it - 1) * 32 + tid];
    cinv[tid] = (ct > 0) ? (1.0 / (double)ct) : 0.0;  // 32 divs instead of 8192
  }
  __syncthreads();
  // centroids: it==0 -> cent0 ; else cnt>0 ? (sum of 4 replicas)*inv : centprev
  if (it == 0) {
    for (int rep = 0; rep < 32; ++rep) csT[tid][rep] = cent0[rep * FF + tid];
  } else {
    for (int rep = 0; rep < 32; ++rep) {
      double ci = cinv[rep];
      double v;
      if (ci != 0.0) {
        double s = 0.;
#pragma unroll
        for (int rr = 0; rr < 4; ++rr)
          s += cent_sum4[(((size_t)(it - 1) * 4 + rr) * 32 + rep) * FF + tid];
        v = s * ci;
      } else {
        v = centprev[((size_t)(it - 1) * 32 + rep) * FF + tid];
      }
      csT[tid][rep] = v;
    }
  }
  __syncthreads();
  if (g < 32) centprev[((size_t)it * 32 + g) * FF + tid] = csT[tid][g];  // empty-cluster chain

  if (tid < 32) {
    double s = 0.;
    for (int k = 0; k < FF; ++k) { double cv = csT[k][tid]; s += cv * cv; }
    c2s[tid] = s;
  }

  int lane = tid & 63, w = tid >> 6;
  int prow = (w >> 1) * 16, ccol = (w & 1) * 16;
  int r16 = lane & 15, kg = lane >> 4;
  double4_t acc = {0.0, 0.0, 0.0, 0.0};
  for (int kt = 0; kt < FF; kt += 4) {
    double a = (double)ps[prow + r16][kt + kg];
    double bv = csT[kt + kg][ccol + r16];
    acc = __builtin_amdgcn_mfma_f64_16x16x4f64(a, bv, acc, 0, 0, 0);
  }
  if (tid < 2) { probe_raw[tid][0] = acc[0]; probe_raw[tid][1] = acc[1]; }
  __syncthreads();

  if (tid < 192) {  // asymmetric layout probes
    int pw = tid >> 6;                  // 0:(0,0) 1:(0,1) 2:(1,0)
    int pr = (pw == 2) ? 1 : 0;
    int pc = (pw == 1) ? 1 : 0;
    double partial = 0.0;
#pragma unroll
    for (int kk = 0; kk < 4; ++kk)
      partial += (double)ps[pr][lane * 4 + kk] * csT[lane * 4 + kk][pc];
    for (int off = 32; off; off >>= 1) partial += __shfl_xor(partial, off, 64);
    if (lane == 0) want[pw] = partial;
  }
  __syncthreads();
  if (tid == 0) {
    double w00 = want[0], w01 = want[1], w10 = want[2];
    double m00 = probe_raw[0][0], mA = probe_raw[1][0], mB = probe_raw[0][1];
    auto near = [](double a, double b) { return fabs(a - b) <= 1e-9 * (1.0 + fabs(b)); };
    bool ok00 = near(m00, w00);
    bool h1 = ok00 && near(mA, w01) && near(mB, w10);
    bool h2 = ok00 && near(mB, w01) && near(mA, w10);
    hyp = h1 ? 0 : (h2 ? 1 : 2);
  }
  __syncthreads();
  int hh = hyp;
  if (hh == 0) {
#pragma unroll
    for (int ii = 0; ii < 4; ++ii) {
      int row = prow + kg * 4 + ii, col = ccol + r16;
      d2s[row][col] = (p2[g * 32 + row] - 2.0 * acc[ii]) + c2s[col];
    }
  } else if (hh == 1) {
#pragma unroll
    for (int ii = 0; ii < 4; ++ii) {
      int row = prow + r16, col = ccol + kg * 4 + ii;
      d2s[row][col] = (p2[g * 32 + row] - 2.0 * acc[ii]) + c2s[col];
    }
  }
  __syncthreads();
  if (hh == 2) {  // proven scalar fallback (block-uniform)
    int p0 = tid >> 4, c0 = tid & 15;
    double a00 = 0., a01 = 0., a10 = 0., a11 = 0.;
    for (int k = 0; k < FF; ++k) {
      double pa = (double)ps[p0][k], pb = (double)ps[p0 + 16][k];
      double ca = csT[k][c0], cb = csT[k][c0 + 16];
      a00 += pa * ca; a01 += pa * cb; a10 += pb * ca; a11 += pb * cb;
    }
    double pp0 = p2[g * 32 + p0], pp1 = p2[g * 32 + p0 + 16];
    double cc0 = c2s[c0], cc1 = c2s[c0 + 16];
    d2s[p0][c0]           = (pp0 - 2.0 * a00) + cc0;
    d2s[p0][c0 + 16]      = (pp0 - 2.0 * a01) + cc1;
    d2s[p0 + 16][c0]      = (pp1 - 2.0 * a10) + cc0;
    d2s[p0 + 16][c0 + 16] = (pp1 - 2.0 * a11) + cc1;
  }
  __syncthreads();

  if (tid < 32) {
    double m = d2s[tid][0];
    int idx = 0;
    for (int c = 1; c < 32; ++c) {
      double v = d2s[tid][c];
      if (v < m) { m = v; idx = c; }  // strict <: first-wins like argmin
    }
    as[tid] = idx;
    assignI[g * 32 + tid] = idx;
    if (conceptsF) conceptsF[g * 32 + tid] = (float)idx;
  }
  if (it == KITERS) return;  // final assign: no accumulation

  double* accm = &csT[0][0];  // reuse csT storage
  for (int r = 0; r < 32; ++r) accm[r * 258 + tid] = 0.0;
  __syncthreads();
  for (int r = 0; r < 32; ++r) { int s = as[r]; accm[s * 258 + tid] += (double)ps[r][tid]; }
  if (tid < 32) {
    int c = 0;
    for (int r = 0; r < 32; ++r) c += (as[r] == tid) ? 1 : 0;
    lcs[tid] = c;
    if (c > 0) atomicAdd(&cntI[it * 32 + tid], c);
  }
  __syncthreads();
  int rr = g & 3;  // replica: 4x less per-address contention
  for (int r = 0; r < 32; ++r) {
    if (lcs[r] > 0)
      unsafeAtomicAdd(&cent_sum4[(((size_t)it * 4 + rr) * 32 + r) * FF + tid],
                      accm[r * 258 + tid]);
  }
}

// ---------- connected components: inline concept-filtered lists + early exit + scan ----------
__global__ __launch_bounds__(512) void components_kernel(const unsigned long long* __restrict__ adjbits,
                                                         const int* __restrict__ concepts,
                                                         int* __restrict__ comp,
                                                         float* __restrict__ maskF) {
  __shared__ int cI[512];
  __shared__ unsigned short LT[FMAXD][512];
  __shared__ int lab[512];
  __shared__ int ids[512];
  int b = blockIdx.x, t = threadIdx.x;
  cI[t] = concepts[b * NN + t];
  __syncthreads();
  int ci = cI[t];
  const unsigned long long* brow = adjbits + ((size_t)(b * NN + t)) * 8;
  int fd = 0;
#pragma unroll
  for (int q = 0; q < 8; ++q) {
    unsigned long long bits = brow[q];
    while (bits) {
      int j = (q << 6) + __builtin_ctzll(bits);
      bits &= bits - 1;
      if (cI[j] == ci) { if (fd < FMAXD) LT[fd][t] = (unsigned short)j; ++fd; }
    }
  }
  if (fd > FMAXD) fd = FMAXD;
  lab[t] = t;
  __syncthreads();
  for (int it = 0; it < CCITERS; ++it) {
    int old = lab[t];
    int m = old;
    for (int n = 0; n < fd; ++n) m = min(m, lab[LT[n][t]]);
    __syncthreads();
    lab[t] = m;
    __syncthreads();
    int a = lab[m];
    __syncthreads();
    lab[t] = a;
    __syncthreads();
    int a2 = lab[a];
    __syncthreads();
    lab[t] = a2;
    int changed = (a2 != old) ? 1 : 0;
    if (__syncthreads_or(changed) == 0) break;  // fixed point: rest are identity
  }
  // inclusive scan of is_root (Hillis-Steele, exact integer)
  ids[t] = (lab[t] == t) ? 1 : 0;
  __syncthreads();
  for (int off = 1; off < 512; off <<= 1) {
    int v = (t >= off) ? ids[t - off] : 0;
    __syncthreads();
    ids[t] += v;
    __syncthreads();
  }
  comp[b * NN + t] = ids[lab[t]];
  maskF[b * NN + t] = (t < ids[511]) ? 1.0f : 0.0f;
}

// ---------- segment sum x_new ----------
__global__ __launch_bounds__(256) void xnew_kernel(const float* __restrict__ H,
                                                   const int* __restrict__ comp,
                                                   float* __restrict__ xnew) {
  int i = blockIdx.x, b = blockIdx.y, f = threadIdx.x;
  int s = comp[b * NN + i] - 1;
  atomicAdd(&xnew[((size_t)(b * NN + s)) * FF + f], H[((size_t)(b * NN + i)) * FF + f]);
}

// ---------- adj_new from adjbits (adj in {0,1}) ----------
__global__ __launch_bounds__(64) void adjnew_kernel(const unsigned long long* __restrict__ adjbits,
                                                    const int* __restrict__ comp,
                                                    float* __restrict__ out) {
  int b = blockIdx.y, lane = threadIdx.x;
  int i = blockIdx.x * 8 + (lane >> 3);
  int q = lane & 7;
  unsigned long long bits = adjbits[((size_t)(b * NN + i)) * 8 + q];
  if (!bits) return;
  int si = comp[b * NN + i] - 1;
  float* ob = out + (size_t)b * NN * NN;
  while (bits) {
    int j = (q << 6) + __builtin_ctzll(bits);
    bits &= bits - 1;
    int sj = comp[b * NN + j] - 1;
    ob[(size_t)si * NN + sj] = 1.0f;  // all writers write 1.0 -> benign race
  }
}

extern "C" void kernel_launch(void* const* d_in, const int* in_sizes, int n_in,
                              void* d_out, int out_size, void* d_ws, size_t ws_size,
                              hipStream_t stream) {
  (void)in_sizes; (void)n_in; (void)out_size; (void)ws_size;
  const float* x   = (const float*)d_in[0];
  const float* adj = (const float*)d_in[1];
  const float* W1 = (const float*)d_in[3];
  const float* b1 = (const float*)d_in[4];
  const float* W2 = (const float*)d_in[5];
  const float* b2 = (const float*)d_in[6];

  float* out = (float*)d_out;
  float* xnew      = out;                       // 2097152 f
  float* adjnew    = out + 2097152;             // 4194304 f
  float* conceptsF = out + 6291456;             // 8192 f
  float* hout      = out + 6299648;             // 2097152 f
  float* maskF     = out + 8396800;             // 8192 f

  char* ws = (char*)d_ws;
  double* dinv = (double*)(ws + 0);                    // 64 KB
  float*  y    = (float*)(ws + 65536);                 // 8 MB, ends 8454144
  // kmeans buffers overlay h1 region (h1 dead after gemm2; zeroed in spmv2):
  float*  h1   = (float*)(ws + 8454144);               // 8 MB, ends 16842752
  double* centprev  = (double*)(ws + 8454144);         // 11*32*256*8 = 720896 -> 9175040
  double* cent_sum4 = (double*)(ws + 9175040);         // 4*720896 = 2883584 -> 12058624
  int*    cntI      = (int*)(ws + 12058624);           // 1408 -> 12060032
  // zero range: 9175040..12060032 = 2884992 B -> 705 chunks of 4096
  double* cent0 = (double*)(ws + 16842752);            // 64 KB
  double* p2    = (double*)(ws + 16908544);            // 64 KB
  unsigned long long* adjbits = (unsigned long long*)(ws + 16974080);  // 512 KB -> 17498368
  int* assignI = (int*)(ws + 17498368);                // 32 KB (aliased as degv early)
  int* comp    = (int*)(ws + 17531136);                // 32 KB -> 17563904
  int* degv    = assignI;  // degv dead before assignI's first write
  unsigned short* nbr = (unsigned short*)xnew;         // 1.5 MB in xnew region (pre-memset)

  // adj_new no longer scratch -> zero it first
  hipMemsetAsync(adjnew, 0, (size_t)4194304 * sizeof(float), stream);

  // one pass over adj: bits + neighbor lists + normalization
  build_adjbits<<<dim3(NN, BB), 64, 0, stream>>>(adj, adjbits, dinv, nbr, degv);

  // GCN layer 1 and 2 (spmv2 also emits p2/cent0 and zeroes kmeans accumulators)
  gemm_scale<<<dim3(8, 4, BB), 256, 0, stream>>>(x, W1, dinv, y);
  spmv_relu<<<dim3(NN, BB), 256, 0, stream>>>(y, nbr, degv, adjbits, dinv, b1, h1,
                                              nullptr, nullptr, nullptr, 0);
  gemm_scale<<<dim3(8, 4, BB), 256, 0, stream>>>(h1, W2, dinv, y);
  spmv_relu<<<dim3(NN, BB), 256, 0, stream>>>(y, nbr, degv, adjbits, dinv, b2, hout,
                                              p2, cent0, (char*)cent_sum4, 705);

  // nbr (in xnew region) now dead -> zero x_new
  hipMemsetAsync(xnew, 0, (size_t)2097152 * sizeof(float), stream);

  // kmeans: 11 launches, update folded into next assign via replica atomic sums
  const float* pts = hout;
  for (int it = 0; it <= KITERS; ++it) {
    kmeans_it<<<256, 256, 0, stream>>>(pts, cent0, centprev, cent_sum4, cntI, p2,
                                       assignI, (it == KITERS) ? conceptsF : nullptr, it);
  }

  // connected components (build_bits inlined)
  components_kernel<<<BB, 512, 0, stream>>>(adjbits, assignI, comp, maskF);

  // segment reductions
  xnew_kernel<<<dim3(NN, BB), 256, 0, stream>>>(hout, comp, xnew);
  adjnew_kernel<<<dim3(64, BB), 64, 0, stream>>>(adjbits, comp, adjnew);
}

// Round 11
// 623.661 us; speedup vs baseline: 1.0073x; 1.0073x over previous
//
#include <hip/hip_runtime.h>
#include <cstdint>
#include <cstddef>

#define BB 16
#define NN 512
#define FF 256
#define NC 32
#define KITERS 10
#define CCITERS 20
#define MAXD 96    // cap for full-adjacency neighbor list (mean deg ~20)
#define FMAXD 64   // cap for same-concept filtered list

typedef __attribute__((ext_vector_type(4))) double double4_t;

// ---------- adjacency bits + neighbor list + degree normalization ----------
__global__ __launch_bounds__(64) void build_adjbits(const float* __restrict__ adj,
                                                    unsigned long long* __restrict__ adjbits,
                                                    double* __restrict__ dinv,
                                                    unsigned short* __restrict__ nbr,
                                                    int* __restrict__ degv) {
  int i = blockIdx.x, b = blockIdx.y, lane = threadIdx.x;
  const float* row = adj + ((size_t)(b * NN + i)) * NN;
  unsigned long long lmask = (1ULL << lane) - 1ULL;
  int base = 0;
#pragma unroll
  for (int q = 0; q < 8; ++q) {
    bool pred = (row[q * 64 + lane] != 0.0f);
    unsigned long long m = __ballot(pred ? 1 : 0);
    if (lane == 0) adjbits[((size_t)(b * NN + i)) * 8 + q] = m;
    if (pred) {
      int pos = base + __popcll(m & lmask);
      if (pos < MAXD) nbr[((size_t)(b * NN + i)) * MAXD + pos] = (unsigned short)(q * 64 + lane);
    }
    base += __popcll(m);
  }
  if (lane == 0) {
    degv[b * NN + i] = base;
    double tot = (double)base + 1.0;  // a = adj + I; clip no-op since >=1
    dinv[b * NN + i] = 1.0 / sqrt(tot);
  }
}

// ---------- GEMM: Y[b] = dinv_row * (X[b] @ W), fp64 accumulate (proven scalar) ----------
__global__ __launch_bounds__(256) void gemm_scale(const float* __restrict__ X,
                                                  const float* __restrict__ W,
                                                  const double* __restrict__ dinv,
                                                  float* __restrict__ Y) {
  __shared__ float As[16][68];
  __shared__ float Bs[16][64];
  int bm = blockIdx.x, bn = blockIdx.y, b = blockIdx.z;
  int tid = threadIdx.x;
  int tx = tid & 15, ty = tid >> 4;
  const float* Xb = X + (size_t)b * NN * FF;
  float* Yb = Y + (size_t)b * NN * FF;
  double acc[4][4] = {};
  for (int kt = 0; kt < FF; kt += 16) {
    {
      int m = tid >> 2, kq = (tid & 3) * 4;
      const float4 v = *(const float4*)&Xb[(size_t)(bm * 64 + m) * FF + kt + kq];
      As[kq + 0][m] = v.x; As[kq + 1][m] = v.y; As[kq + 2][m] = v.z; As[kq + 3][m] = v.w;
    }
    {
      int k = tid >> 4, n4 = (tid & 15) * 4;
      *(float4*)&Bs[k][n4] = *(const float4*)&W[(size_t)(kt + k) * FF + bn * 64 + n4];
    }
    __syncthreads();
#pragma unroll
    for (int k = 0; k < 16; ++k) {
      float4 a = *(const float4*)&As[k][ty * 4];
      float4 bv = *(const float4*)&Bs[k][tx * 4];
      double ax = a.x, ay = a.y, az = a.z, aw = a.w;
      double bx = bv.x, by = bv.y, bz = bv.z, bw = bv.w;
      acc[0][0] += ax * bx; acc[0][1] += ax * by; acc[0][2] += ax * bz; acc[0][3] += ax * bw;
      acc[1][0] += ay * bx; acc[1][1] += ay * by; acc[1][2] += ay * bz; acc[1][3] += ay * bw;
      acc[2][0] += az * bx; acc[2][1] += az * by; acc[2][2] += az * bz; acc[2][3] += az * bw;
      acc[3][0] += aw * bx; acc[3][1] += aw * by; acc[3][2] += aw * bz; acc[3][3] += aw * bw;
    }
    __syncthreads();
  }
#pragma unroll
  for (int i = 0; i < 4; ++i) {
    int row = bm * 64 + ty * 4 + i;
    double di = dinv[b * NN + row];
    float4 v;
    v.x = (float)(di * acc[i][0]); v.y = (float)(di * acc[i][1]);
    v.z = (float)(di * acc[i][2]); v.w = (float)(di * acc[i][3]);
    *(float4*)&Yb[(size_t)row * FF + bn * 64 + tx * 4] = v;
  }
}

// ---------- SpMV + optional (p2 / cent0 / kmeans-buffer zeroing) ----------
__global__ __launch_bounds__(256) void spmv_relu(const float* __restrict__ Y,
                                                 const unsigned short* __restrict__ nbr,
                                                 const int* __restrict__ degv,
                                                 const unsigned long long* __restrict__ adjbits,
                                                 const double* __restrict__ dinv,
                                                 const float* __restrict__ bias,
                                                 float* __restrict__ H,
                                                 double* __restrict__ p2out,
                                                 double* __restrict__ cent0,
                                                 char* __restrict__ zbuf,
                                                 int zchunks) {
  __shared__ double red[256];
  int i = blockIdx.x, b = blockIdx.y, f = threadIdx.x;
  int row = b * NN + i;
  const float* Yb = Y + (size_t)b * NN * FF;
  double z = (double)Yb[(size_t)i * FF + f];  // +I term
  int deg = degv[row];
  if (deg <= MAXD) {
    const unsigned short* lst = nbr + (size_t)row * MAXD;
    int n = 0;
    for (; n + 8 <= deg; n += 8) {  // 8-way MLP; same ascending order, same add sequence
      int j0 = lst[n], j1 = lst[n + 1], j2 = lst[n + 2], j3 = lst[n + 3];
      int j4 = lst[n + 4], j5 = lst[n + 5], j6 = lst[n + 6], j7 = lst[n + 7];
      float v0 = Yb[(size_t)j0 * FF + f];
      float v1 = Yb[(size_t)j1 * FF + f];
      float v2 = Yb[(size_t)j2 * FF + f];
      float v3 = Yb[(size_t)j3 * FF + f];
      float v4 = Yb[(size_t)j4 * FF + f];
      float v5 = Yb[(size_t)j5 * FF + f];
      float v6 = Yb[(size_t)j6 * FF + f];
      float v7 = Yb[(size_t)j7 * FF + f];
      z += (double)v0; z += (double)v1; z += (double)v2; z += (double)v3;
      z += (double)v4; z += (double)v5; z += (double)v6; z += (double)v7;
    }
    for (; n < deg; ++n) z += (double)Yb[(size_t)lst[n] * FF + f];
  } else {
    const unsigned long long* brow = adjbits + (size_t)row * 8;
    for (int q = 0; q < 8; ++q) {
      unsigned long long bits = brow[q];
      while (bits) {
        int j = (q << 6) + __builtin_ctzll(bits);
        bits &= bits - 1;
        z += (double)Yb[(size_t)j * FF + f];
      }
    }
  }
  double h = dinv[row] * z + (double)bias[f];
  float hf = (h > 0.0) ? (float)h : 0.0f;
  H[((size_t)row) * FF + f] = hf;

  if (p2out) {  // uniform branch (kernel arg)
    double v = (double)hf;
    red[f] = v * v;
    __syncthreads();
    for (int s = 128; s; s >>= 1) { if (f < s) red[f] += red[f + s]; __syncthreads(); }
    if (f == 0) p2out[row] = red[0];
    if (b == 0 && i < NC) cent0[i * FF + f] = (double)hf;
    if (b == 2 || b == 3) {  // zero kmeans accumulators (dead h1 region)
      int chunk = (b - 2) * 512 + i;
      if (chunk < zchunks) {
        float4 z4 = {0.f, 0.f, 0.f, 0.f};
        ((float4*)(zbuf + (size_t)chunk * 4096))[f] = z4;
      }
    }
  }
}

// ---------- kmeans iteration: centroid recompute + MFMA d2 + argmin + replica atomics ----------
__global__ __launch_bounds__(256) void kmeans_it(const float* __restrict__ pts,
                                                 const double* __restrict__ cent0,
                                                 double* __restrict__ centprev,
                                                 double* __restrict__ cent_sum4,
                                                 int* __restrict__ cntI,
                                                 const double* __restrict__ p2,
                                                 int* __restrict__ assignI,
                                                 float* __restrict__ conceptsF,
                                                 int it) {
  __shared__ float ps[32][260];
  __shared__ double csT[256][35];    // csT[k][c]; reused as acc[32][258]
  __shared__ double d2s[32][33];
  __shared__ double c2s[32];
  __shared__ double cinv[32];
  __shared__ double want[3];
  __shared__ double probe_raw[2][2];
  __shared__ int as[32];
  __shared__ int lcs[32];
  __shared__ int hyp;
  int g = blockIdx.x, tid = threadIdx.x;

  for (int r = 0; r < 32; ++r) ps[r][tid] = pts[(size_t)(g * 32 + r) * FF + tid];
  if (it > 0 && tid < 32) {
    int ct = cntI[(it - 1) * 32 + tid];
    cinv[tid] = (ct > 0) ? (1.0 / (double)ct) : 0.0;
  }
  __syncthreads();
  if (it == 0) {
    for (int rep = 0; rep < 32; ++rep) csT[tid][rep] = cent0[rep * FF + tid];
  } else {
    for (int rep = 0; rep < 32; ++rep) {
      double ci = cinv[rep];
      double v;
      if (ci != 0.0) {
        double s = 0.;
#pragma unroll
        for (int rr = 0; rr < 4; ++rr)
          s += cent_sum4[(((size_t)(it - 1) * 4 + rr) * 32 + rep) * FF + tid];
        v = s * ci;
      } else {
        v = centprev[((size_t)(it - 1) * 32 + rep) * FF + tid];
      }
      csT[tid][rep] = v;
    }
  }
  __syncthreads();
  if (g < 32) centprev[((size_t)it * 32 + g) * FF + tid] = csT[tid][g];  // empty-cluster chain

  if (tid < 32) {
    double s = 0.;
    for (int k = 0; k < FF; ++k) { double cv = csT[k][tid]; s += cv * cv; }
    c2s[tid] = s;
  }

  int lane = tid & 63, w = tid >> 6;
  int prow = (w >> 1) * 16, ccol = (w & 1) * 16;
  int r16 = lane & 15, kg = lane >> 4;
  double4_t acc = {0.0, 0.0, 0.0, 0.0};
  for (int kt = 0; kt < FF; kt += 4) {
    double a = (double)ps[prow + r16][kt + kg];
    double bv = csT[kt + kg][ccol + r16];
    acc = __builtin_amdgcn_mfma_f64_16x16x4f64(a, bv, acc, 0, 0, 0);
  }
  if (tid < 2) { probe_raw[tid][0] = acc[0]; probe_raw[tid][1] = acc[1]; }
  __syncthreads();

  if (tid < 192) {  // asymmetric layout probes
    int pw = tid >> 6;                  // 0:(0,0) 1:(0,1) 2:(1,0)
    int pr = (pw == 2) ? 1 : 0;
    int pc = (pw == 1) ? 1 : 0;
    double partial = 0.0;
#pragma unroll
    for (int kk = 0; kk < 4; ++kk)
      partial += (double)ps[pr][lane * 4 + kk] * csT[lane * 4 + kk][pc];
    for (int off = 32; off; off >>= 1) partial += __shfl_xor(partial, off, 64);
    if (lane == 0) want[pw] = partial;
  }
  __syncthreads();
  if (tid == 0) {
    double w00 = want[0], w01 = want[1], w10 = want[2];
    double m00 = probe_raw[0][0], mA = probe_raw[1][0], mB = probe_raw[0][1];
    auto near = [](double a, double b) { return fabs(a - b) <= 1e-9 * (1.0 + fabs(b)); };
    bool ok00 = near(m00, w00);
    bool h1 = ok00 && near(mA, w01) && near(mB, w10);
    bool h2 = ok00 && near(mB, w01) && near(mA, w10);
    hyp = h1 ? 0 : (h2 ? 1 : 2);
  }
  __syncthreads();
  int hh = hyp;
  if (hh == 0) {
#pragma unroll
    for (int ii = 0; ii < 4; ++ii) {
      int row = prow + kg * 4 + ii, col = ccol + r16;
      d2s[row][col] = (p2[g * 32 + row] - 2.0 * acc[ii]) + c2s[col];
    }
  } else if (hh == 1) {
#pragma unroll
    for (int ii = 0; ii < 4; ++ii) {
      int row = prow + r16, col = ccol + kg * 4 + ii;
      d2s[row][col] = (p2[g * 32 + row] - 2.0 * acc[ii]) + c2s[col];
    }
  }
  __syncthreads();
  if (hh == 2) {  // proven scalar fallback (block-uniform)
    int p0 = tid >> 4, c0 = tid & 15;
    double a00 = 0., a01 = 0., a10 = 0., a11 = 0.;
    for (int k = 0; k < FF; ++k) {
      double pa = (double)ps[p0][k], pb = (double)ps[p0 + 16][k];
      double ca = csT[k][c0], cb = csT[k][c0 + 16];
      a00 += pa * ca; a01 += pa * cb; a10 += pb * ca; a11 += pb * cb;
    }
    double pp0 = p2[g * 32 + p0], pp1 = p2[g * 32 + p0 + 16];
    double cc0 = c2s[c0], cc1 = c2s[c0 + 16];
    d2s[p0][c0]           = (pp0 - 2.0 * a00) + cc0;
    d2s[p0][c0 + 16]      = (pp0 - 2.0 * a01) + cc1;
    d2s[p0 + 16][c0]      = (pp1 - 2.0 * a10) + cc0;
    d2s[p0 + 16][c0 + 16] = (pp1 - 2.0 * a11) + cc1;
  }
  __syncthreads();

  if (tid < 32) {
    double m = d2s[tid][0];
    int idx = 0;
    for (int c = 1; c < 32; ++c) {
      double v = d2s[tid][c];
      if (v < m) { m = v; idx = c; }  // strict <: first-wins like argmin
    }
    as[tid] = idx;
    assignI[g * 32 + tid] = idx;
    if (conceptsF) conceptsF[g * 32 + tid] = (float)idx;
  }
  if (it == KITERS) return;  // final assign: no accumulation

  double* accm = &csT[0][0];  // reuse csT storage
  for (int r = 0; r < 32; ++r) accm[r * 258 + tid] = 0.0;
  __syncthreads();
  for (int r = 0; r < 32; ++r) { int s = as[r]; accm[s * 258 + tid] += (double)ps[r][tid]; }
  if (tid < 32) {
    int c = 0;
    for (int r = 0; r < 32; ++r) c += (as[r] == tid) ? 1 : 0;
    lcs[tid] = c;
    if (c > 0) atomicAdd(&cntI[it * 32 + tid], c);
  }
  __syncthreads();
  int rr = g & 3;  // replica: 4x less per-address contention
  for (int r = 0; r < 32; ++r) {
    if (lcs[r] > 0)
      unsafeAtomicAdd(&cent_sum4[(((size_t)it * 4 + rr) * 32 + r) * FF + tid],
                      accm[r * 258 + tid]);
  }
}

// ---------- connected components: inline concept-filtered lists + early exit + scan ----------
__global__ __launch_bounds__(512) void components_kernel(const unsigned long long* __restrict__ adjbits,
                                                         const int* __restrict__ concepts,
                                                         int* __restrict__ comp,
                                                         float* __restrict__ maskF) {
  __shared__ int cI[512];
  __shared__ unsigned short LT[FMAXD][512];
  __shared__ int lab[512];
  __shared__ int ids[512];
  int b = blockIdx.x, t = threadIdx.x;
  cI[t] = concepts[b * NN + t];
  __syncthreads();
  int ci = cI[t];
  const unsigned long long* brow = adjbits + ((size_t)(b * NN + t)) * 8;
  int fd = 0;
#pragma unroll
  for (int q = 0; q < 8; ++q) {
    unsigned long long bits = brow[q];
    while (bits) {
      int j = (q << 6) + __builtin_ctzll(bits);
      bits &= bits - 1;
      if (cI[j] == ci) { if (fd < FMAXD) LT[fd][t] = (unsigned short)j; ++fd; }
    }
  }
  if (fd > FMAXD) fd = FMAXD;
  lab[t] = t;
  __syncthreads();
  for (int it = 0; it < CCITERS; ++it) {
    int old = lab[t];
    int m = old;
    for (int n = 0; n < fd; ++n) m = min(m, lab[LT[n][t]]);
    __syncthreads();
    lab[t] = m;
    __syncthreads();
    int a = lab[m];
    __syncthreads();
    lab[t] = a;
    __syncthreads();
    int a2 = lab[a];
    __syncthreads();
    lab[t] = a2;
    int changed = (a2 != old) ? 1 : 0;
    if (__syncthreads_or(changed) == 0) break;  // fixed point: rest are identity
  }
  // inclusive scan of is_root (Hillis-Steele, exact integer)
  ids[t] = (lab[t] == t) ? 1 : 0;
  __syncthreads();
  for (int off = 1; off < 512; off <<= 1) {
    int v = (t >= off) ? ids[t - off] : 0;
    __syncthreads();
    ids[t] += v;
    __syncthreads();
  }
  comp[b * NN + t] = ids[lab[t]];
  maskF[b * NN + t] = (t < ids[511]) ? 1.0f : 0.0f;
}

// ---------- merged segment reductions: x_new atomic sum + adj_new scatter ----------
__global__ __launch_bounds__(256) void segred_kernel(const float* __restrict__ H,
                                                     const int* __restrict__ comp,
                                                     const unsigned long long* __restrict__ adjbits,
                                                     float* __restrict__ xnew,
                                                     float* __restrict__ adjnew) {
  int i = blockIdx.x, b = blockIdx.y, f = threadIdx.x;
  int s = comp[b * NN + i] - 1;
  atomicAdd(&xnew[((size_t)(b * NN + s)) * FF + f], H[((size_t)(b * NN + i)) * FF + f]);
  if (f < 8) {  // wave-0 lanes scan this row's adjacency words
    unsigned long long bits = adjbits[((size_t)(b * NN + i)) * 8 + f];
    if (bits) {
      float* ob = adjnew + (size_t)b * NN * NN;
      while (bits) {
        int j = (f << 6) + __builtin_ctzll(bits);
        bits &= bits - 1;
        int sj = comp[b * NN + j] - 1;
        ob[(size_t)s * NN + sj] = 1.0f;  // all writers write 1.0 -> benign race
      }
    }
  }
}

extern "C" void kernel_launch(void* const* d_in, const int* in_sizes, int n_in,
                              void* d_out, int out_size, void* d_ws, size_t ws_size,
                              hipStream_t stream) {
  (void)in_sizes; (void)n_in; (void)out_size; (void)ws_size;
  const float* x   = (const float*)d_in[0];
  const float* adj = (const float*)d_in[1];
  const float* W1 = (const float*)d_in[3];
  const float* b1 = (const float*)d_in[4];
  const float* W2 = (const float*)d_in[5];
  const float* b2 = (const float*)d_in[6];

  float* out = (float*)d_out;
  float* xnew      = out;                       // 2097152 f
  float* adjnew    = out + 2097152;             // 4194304 f
  float* conceptsF = out + 6291456;             // 8192 f
  float* hout      = out + 6299648;             // 2097152 f
  float* maskF     = out + 8396800;             // 8192 f

  char* ws = (char*)d_ws;
  double* dinv = (double*)(ws + 0);                    // 64 KB
  float*  y    = (float*)(ws + 65536);                 // 8 MB, ends 8454144
  float*  h1   = (float*)(ws + 8454144);               // 8 MB, ends 16842752
  double* centprev  = (double*)(ws + 8454144);         // 720896 -> 9175040
  double* cent_sum4 = (double*)(ws + 9175040);         // 2883584 -> 12058624
  int*    cntI      = (int*)(ws + 12058624);           // 1408 -> 12060032
  double* cent0 = (double*)(ws + 16842752);            // 64 KB
  double* p2    = (double*)(ws + 16908544);            // 64 KB
  unsigned long long* adjbits = (unsigned long long*)(ws + 16974080);  // 512 KB -> 17498368
  int* assignI = (int*)(ws + 17498368);                // 32 KB (aliased as degv early)
  int* comp    = (int*)(ws + 17531136);                // 32 KB -> 17563904
  int* degv    = assignI;  // degv dead before assignI's first write
  unsigned short* nbr = (unsigned short*)xnew;         // 1.5 MB in xnew region (pre-memset)

  // adj_new no longer scratch -> zero it first
  hipMemsetAsync(adjnew, 0, (size_t)4194304 * sizeof(float), stream);

  // one pass over adj: bits + neighbor lists + normalization
  build_adjbits<<<dim3(NN, BB), 64, 0, stream>>>(adj, adjbits, dinv, nbr, degv);

  // GCN layer 1 and 2 (spmv2 also emits p2/cent0 and zeroes kmeans accumulators)
  gemm_scale<<<dim3(8, 4, BB), 256, 0, stream>>>(x, W1, dinv, y);
  spmv_relu<<<dim3(NN, BB), 256, 0, stream>>>(y, nbr, degv, adjbits, dinv, b1, h1,
                                              nullptr, nullptr, nullptr, 0);
  gemm_scale<<<dim3(8, 4, BB), 256, 0, stream>>>(h1, W2, dinv, y);
  spmv_relu<<<dim3(NN, BB), 256, 0, stream>>>(y, nbr, degv, adjbits, dinv, b2, hout,
                                              p2, cent0, (char*)cent_sum4, 705);

  // nbr (in xnew region) now dead -> zero x_new
  hipMemsetAsync(xnew, 0, (size_t)2097152 * sizeof(float), stream);

  // kmeans: 11 launches, update folded into next assign via replica atomic sums
  const float* pts = hout;
  for (int it = 0; it <= KITERS; ++it) {
    kmeans_it<<<256, 256, 0, stream>>>(pts, cent0, centprev, cent_sum4, cntI, p2,
                                       assignI, (it == KITERS) ? conceptsF : nullptr, it);
  }

  // connected components (build_bits inlined)
  components_kernel<<<BB, 512, 0, stream>>>(adjbits, assignI, comp, maskF);

  // merged segment reductions (x_new + adj_new)
  segred_kernel<<<dim3(NN, BB), 256, 0, stream>>>(hout, comp, adjbits, xnew, adjnew);
}